// Round 13
// baseline (31.898 us; speedup 1.0000x reference)
//
#include <hip/hip_runtime.h>
#include <math.h>

#define BTPB 1024
#define PTPB 256
#define NWAVE (PTPB / 64)
#define NCELL 9
#define NCELL3 729
#define CAPC 40                 // per-cell bucket capacity (avg 8.4; overflow->flag)
#define CAP (27 * CAPC)         // staged max = 1080 (guaranteed if no overflow)
#define PI_F 3.14159265358979323846f
#define EPS_F 1e-12f

__device__ __forceinline__ float wave_reduce(float v) {
#pragma unroll
    for (int off = 32; off > 0; off >>= 1) v += __shfl_down(v, off, 64);
    return v;
}

template<int NT>
__device__ __forceinline__ float block_reduce(float v, float* sbuf) {
    v = wave_reduce(v);
    int lane = threadIdx.x & 63;
    int wid  = threadIdx.x >> 6;
    if (lane == 0) sbuf[wid] = v;
    __syncthreads();
    float r = 0.0f;
    if (threadIdx.x == 0) {
        for (int w = 0; w < NT / 64; ++w) r += sbuf[w];
    }
    return r;
}

__device__ __forceinline__ int cell_coord(float x) {
    int c = (int)floorf(x * (float)NCELL);
    return min(max(c, 0), NCELL - 1);
}

__device__ __forceinline__ void pair_math(float xix, float xiy, float xiz,
                                          float vix, float viy, float viz,
                                          float ax, float ay, float az,
                                          float bx, float by, float bz,
                                          float inv_h, float h2,
                                          float& wacc, float& dacc) {
    float dx = xix - ax, dy = xiy - ay, dz = xiz - az;
    float d2 = fmaf(dx, dx, fmaf(dy, dy, dz * dz));
    float r2c = fmaxf(d2, EPS_F);
    float ir  = rsqrtf(r2c);
    float r   = r2c * ir;
    float q   = r * inv_h;
    bool inm = (d2 <= h2) && (q <= 1.0f);
    bool lo  = (q <= 0.5f);
    float q2 = q * q, om = 1.0f - q, om2 = om * om;
    float w  = lo ? fmaf(6.0f, q2 * q - q2, 1.0f) : 2.0f * om2 * om;
    wacc += inm ? w : 0.0f;
    float dw = lo ? q * fmaf(18.0f, q, -12.0f) : -6.0f * om2;
    dw = inm ? dw : 0.0f;
    float irm = (d2 > EPS_F) ? ir : 0.0f;
    float dvx = bx - vix, dvy = by - viy, dvz = bz - viz;
    float dot = fmaf(dvx, dx, fmaf(dvy, dy, dvz * dz));
    dacc = fmaf(dw * irm, dot, dacc);
}

// ---- K1: bin particles into per-cell buckets (scan-once) + loss1 ----
__global__ void __launch_bounds__(BTPB) k_bin(
    const float* __restrict__ pred, const float* __restrict__ y,
    const float* __restrict__ mid_pos, const float* __restrict__ mid_vel,
    const float* __restrict__ y_mean, const float* __restrict__ y_std,
    const float* __restrict__ dt_p, const int* __restrict__ nb_p,
    float4* __restrict__ pos_b, float2* __restrict__ vel_b,
    int* __restrict__ count, float* __restrict__ out, int N, float invN)
{
    __shared__ float sred[BTPB / 64];
    int tid = threadIdx.x;
    int i = blockIdx.x * BTPB + tid;
    float t1 = 0.0f;
    if (i < N) {
        int nb = nb_p[0];
        float inv_dt = 1.0f / dt_p[0];
        float y0 = y[i * 3 + 0], y1 = y[i * 3 + 1], y2 = y[i * 3 + 2];
        float p0 = pred[i * 3 + 0], p1 = pred[i * 3 + 1], p2 = pred[i * 3 + 2];
        float d0 = y0 - p0, d1 = y1 - p1, d2 = y2 - p2;
        t1 = fmaf(d0, d0, fmaf(d1, d1, d2 * d2));
        bool fluid = (i >= nb);
        float i0 = fluid ? fmaf(y0, y_std[0], y_mean[0]) : 0.0f;
        float i1 = fluid ? fmaf(y1, y_std[1], y_mean[1]) : 0.0f;
        float i2 = fluid ? fmaf(y2, y_std[2], y_mean[2]) : 0.0f;
        float px = mid_pos[i * 3 + 0] + i0;
        float py = mid_pos[i * 3 + 1] + i1;
        float pz = mid_pos[i * 3 + 2] + i2;
        float vx = mid_vel[i * 3 + 0] + i0 * inv_dt;
        float vy = mid_vel[i * 3 + 1] + i1 * inv_dt;
        float vz = mid_vel[i * 3 + 2] + i2 * inv_dt;
        int c = (cell_coord(px) * NCELL + cell_coord(py)) * NCELL + cell_coord(pz);
        int slot = atomicAdd(&count[c], 1);
        if (slot < CAPC) {
            pos_b[c * CAPC + slot] = make_float4(px, py, pz, vx);
            vel_b[c * CAPC + slot] = make_float2(vy, vz);
        } else {
            atomicExch(&count[NCELL3], 1);    // overflow flag
        }
    }
    float s = block_reduce<BTPB>(t1, sred);
    if (tid == 0) atomicAdd(out, s * invN);
}

// ---- K2: one block per cell; flat staged gather; home contiguous at r=13 ----
__global__ void __launch_bounds__(PTPB) k_pairs(
    const float4* __restrict__ pos_b, const float2* __restrict__ vel_b,
    const int* __restrict__ count,
    const float* __restrict__ y, const float* __restrict__ mid_pos,
    const float* __restrict__ mid_vel,
    const float* __restrict__ y_mean, const float* __restrict__ y_std,
    const float* __restrict__ dt_p, const int* __restrict__ nb_p,
    const float* __restrict__ h_p, const float* __restrict__ vol_p,
    float* __restrict__ out, int N, float coef /* 0.1/N */)
{
    __shared__ float4 sh4[CAP];
    __shared__ float2 sh2[CAP];
    __shared__ int s_cid[27];
    __shared__ int s_off[28];
    __shared__ float sred[PTPB / 64];

    int b = blockIdx.x;
    if (count[b] == 0) return;            // empty home cell (pre-barrier, uniform)
    int flag = count[NCELL3];

    int tid = threadIdx.x;
    int ln = tid & 63, wv = tid >> 6;
    int cx = b / (NCELL * NCELL), cy = (b / NCELL) % NCELL, cz = b % NCELL;

    float h = h_p[0], inv_h = 1.0f / h, h2 = h * h;
    float vol = vol_p[0];
    float sigma = 8.0f / (PI_F * h * h * h);
    float acc = 0.0f;

    if (flag == 0) {
        // parallel neighbor counts (one latency round)
        if (tid < 27) {
            int nx = cx + tid / 9 - 1;
            int ny = cy + (tid / 3) % 3 - 1;
            int nz = cz + tid % 3 - 1;
            bool valid = ((unsigned)nx < NCELL) && ((unsigned)ny < NCELL) &&
                         ((unsigned)nz < NCELL);
            int c = valid ? (nx * NCELL + ny) * NCELL + nz : 0;
            s_cid[tid] = valid ? c : -1;
            s_off[tid] = valid ? count[c] : 0;   // flag==0 => count <= CAPC
        }
        __syncthreads();
        if (tid == 0) {
            int a = 0;
            for (int r = 0; r < 27; ++r) { int t = s_off[r]; s_off[r] = a; a += t; }
            s_off[27] = a;
        }
        __syncthreads();
        int T = s_off[27];

        // flat staged gather (consecutive lanes in a subcell -> coalesced)
        for (int g = tid; g < T; g += PTPB) {
            int lo = 0, hi = 26;
            while (lo < hi) {
                int mid = (lo + hi + 1) >> 1;
                if (s_off[mid] <= g) lo = mid; else hi = mid - 1;
            }
            int c = s_cid[lo];
            int w = g - s_off[lo];
            sh4[g] = pos_b[c * CAPC + w];
            sh2[g] = vel_b[c * CAPC + w];
        }
        __syncthreads();

        // home particles are contiguous: subcell r=13 (dx=dy=dz=0)
        int h0 = s_off[13], h1 = s_off[14];
        for (int hp = h0 + wv; hp < h1; hp += NWAVE) {
            float4 me4 = sh4[hp];
            float2 me2 = sh2[hp];
            float wacc = 0.0f, dacc = 0.0f;
            for (int j = ln; j < T; j += 64) {
                float4 a  = sh4[j];
                float2 b2 = sh2[j];
                pair_math(me4.x, me4.y, me4.z, me4.w, me2.x, me2.y,
                          a.x, a.y, a.z, a.w, b2.x, b2.y, inv_h, h2, wacc, dacc);
            }
            wacc = wave_reduce(wacc);
            dacc = wave_reduce(dacc);
            if (ln == 0) {
                acc += fabsf(fmaf(vol * sigma, wacc, -1.0f))
                     + fabsf(vol * (sigma / h) * dacc);
            }
        }
    } else {
        // overflow fallback (never for this input): self-scan from global
        int nb = nb_p[0];
        float inv_dt = 1.0f / dt_p[0];
        float ym0 = y_mean[0], ym1 = y_mean[1], ym2 = y_mean[2];
        float ys0 = y_std[0],  ys1 = y_std[1],  ys2 = y_std[2];
        for (int i = wv; i < N; i += NWAVE) {
            float y0 = y[i * 3 + 0], y1 = y[i * 3 + 1], y2 = y[i * 3 + 2];
            bool fluid = (i >= nb);
            float i0 = fluid ? fmaf(y0, ys0, ym0) : 0.0f;
            float i1 = fluid ? fmaf(y1, ys1, ym1) : 0.0f;
            float i2 = fluid ? fmaf(y2, ys2, ym2) : 0.0f;
            float xix = mid_pos[i * 3 + 0] + i0;
            float xiy = mid_pos[i * 3 + 1] + i1;
            float xiz = mid_pos[i * 3 + 2] + i2;
            bool isH = (cell_coord(xix) == cx) && (cell_coord(xiy) == cy) &&
                       (cell_coord(xiz) == cz);
            if (!isH) continue;
            float vix = mid_vel[i * 3 + 0] + i0 * inv_dt;
            float viy = mid_vel[i * 3 + 1] + i1 * inv_dt;
            float viz = mid_vel[i * 3 + 2] + i2 * inv_dt;
            float wacc = 0.0f, dacc = 0.0f;
            for (int j = ln; j < N; j += 64) {
                float jy0 = y[j * 3 + 0], jy1 = y[j * 3 + 1], jy2 = y[j * 3 + 2];
                bool jf = (j >= nb);
                float j0 = jf ? fmaf(jy0, ys0, ym0) : 0.0f;
                float j1 = jf ? fmaf(jy1, ys1, ym1) : 0.0f;
                float j2 = jf ? fmaf(jy2, ys2, ym2) : 0.0f;
                float ax = mid_pos[j * 3 + 0] + j0;
                float ay = mid_pos[j * 3 + 1] + j1;
                float az = mid_pos[j * 3 + 2] + j2;
                float bx = mid_vel[j * 3 + 0] + j0 * inv_dt;
                float by = mid_vel[j * 3 + 1] + j1 * inv_dt;
                float bz = mid_vel[j * 3 + 2] + j2 * inv_dt;
                pair_math(xix, xiy, xiz, vix, viy, viz,
                          ax, ay, az, bx, by, bz, inv_h, h2, wacc, dacc);
            }
            wacc = wave_reduce(wacc);
            dacc = wave_reduce(dacc);
            if (ln == 0) {
                acc += fabsf(fmaf(vol * sigma, wacc, -1.0f))
                     + fabsf(vol * (sigma / h) * dacc);
            }
        }
        __syncthreads();
    }

    float tot = block_reduce<PTPB>(acc, sred);
    if (tid == 0) atomicAdd(out, coef * tot);
}

extern "C" void kernel_launch(void* const* d_in, const int* in_sizes, int n_in,
                              void* d_out, int out_size, void* d_ws, size_t ws_size,
                              hipStream_t stream) {
    const float* pred    = (const float*)d_in[0];
    const float* y       = (const float*)d_in[1];
    const float* mid_pos = (const float*)d_in[2];
    const float* mid_vel = (const float*)d_in[3];
    const float* y_mean  = (const float*)d_in[4];
    const float* y_std   = (const float*)d_in[5];
    const float* h_p     = (const float*)d_in[6];
    const float* vol_p   = (const float*)d_in[7];
    // d_in[8] = rho_0 (cancels algebraically)
    const float* dt_p    = (const float*)d_in[9];
    const int*   nb_p    = (const int*)d_in[10];

    int N = in_sizes[0] / 3;
    float invN = 1.0f / (float)N;
    int nB = (N + BTPB - 1) / BTPB;

    char* wsb = (char*)d_ws;
    float4* pos_b = (float4*)wsb;     wsb += (size_t)NCELL3 * CAPC * sizeof(float4);
    float2* vel_b = (float2*)wsb;     wsb += (size_t)NCELL3 * CAPC * sizeof(float2);
    int*    count = (int*)wsb;        // NCELL3 + 1 (flag)

    float* out = (float*)d_out;

    hipMemsetAsync(count, 0, (NCELL3 + 1) * sizeof(int), stream);
    hipMemsetAsync(out, 0, sizeof(float), stream);

    k_bin<<<nB, BTPB, 0, stream>>>(pred, y, mid_pos, mid_vel, y_mean, y_std,
                                   dt_p, nb_p, pos_b, vel_b, count, out, N, invN);

    k_pairs<<<NCELL3, PTPB, 0, stream>>>(pos_b, vel_b, count,
                                         y, mid_pos, mid_vel, y_mean, y_std,
                                         dt_p, nb_p, h_p, vol_p,
                                         out, N, 0.1f * invN);
}

// Round 14
// 16.985 us; speedup vs baseline: 1.8780x; 1.8780x over previous
//
#include <hip/hip_runtime.h>
#include <math.h>

#define TPB 1024
#define NBLK 243       // 9 x 9 x 3: home = z-column of 3 cells
#define NWAVE (TPB / 64)
#define NCELL 9
#define CAP 1024       // LDS staging capacity (column neighborhood mean ~380)
#define HCAP 1024
#define PI_F 3.14159265358979323846f
#define EPS_F 1e-12f

__device__ __forceinline__ float wave_reduce(float v) {
#pragma unroll
    for (int off = 32; off > 0; off >>= 1) v += __shfl_down(v, off, 64);
    return v;
}

// valid on thread 0 only; all threads must call
template<int NT>
__device__ __forceinline__ float block_reduce(float v, float* sbuf) {
    v = wave_reduce(v);
    int lane = threadIdx.x & 63;
    int wid  = threadIdx.x >> 6;
    if (lane == 0) sbuf[wid] = v;
    __syncthreads();
    float r = 0.0f;
    if (threadIdx.x == 0) {
        for (int w = 0; w < NT / 64; ++w) r += sbuf[w];
    }
    return r;
}

__device__ __forceinline__ int cell_coord(float x) {
    int c = (int)floorf(x * (float)NCELL);
    return min(max(c, 0), NCELL - 1);
}

__device__ __forceinline__ void pair_math(float xix, float xiy, float xiz,
                                          float vix, float viy, float viz,
                                          float ax, float ay, float az,
                                          float bx, float by, float bz,
                                          float inv_h, float h2,
                                          float& wacc, float& dacc) {
    float dx = xix - ax, dy = xiy - ay, dz = xiz - az;
    float d2 = fmaf(dx, dx, fmaf(dy, dy, dz * dz));
    float r2c = fmaxf(d2, EPS_F);
    float ir  = rsqrtf(r2c);
    float r   = r2c * ir;
    float q   = r * inv_h;
    bool inm = (d2 <= h2) && (q <= 1.0f);
    bool lo  = (q <= 0.5f);
    float q2 = q * q, om = 1.0f - q, om2 = om * om;
    float w  = lo ? fmaf(6.0f, q2 * q - q2, 1.0f) : 2.0f * om2 * om;
    wacc += inm ? w : 0.0f;
    float dw = lo ? q * fmaf(18.0f, q, -12.0f) : -6.0f * om2;
    dw = inm ? dw : 0.0f;
    float irm = (d2 > EPS_F) ? ir : 0.0f;
    float dvx = bx - vix, dvy = by - viy, dvz = bz - viz;
    float dot = fmaf(dvx, dx, fmaf(dvy, dy, dvz * dz));
    dacc = fmaf(dw * irm, dot, dacc);
}

__global__ void __launch_bounds__(TPB) k_main(
    const float* __restrict__ pred, const float* __restrict__ y,
    const float* __restrict__ mid_pos, const float* __restrict__ mid_vel,
    const float* __restrict__ y_mean, const float* __restrict__ y_std,
    const float* __restrict__ h_p, const float* __restrict__ vol_p,
    const float* __restrict__ dt_p, const int* __restrict__ nb_p,
    float* __restrict__ part2, int N, float invN)
{
    __shared__ float4 sh4[CAP];      // pos.xyz, vel.x
    __shared__ float2 sh2[CAP];      // vel.yz
    __shared__ short  s_home[HCAP];  // LDS slot index of home particles
    __shared__ int    s_cnt, s_hcnt;
    __shared__ float  sred[NWAVE];

    int b   = blockIdx.x;
    int tid = threadIdx.x;
    int cx = b / 27, cy = (b / 3) % 9, czg = b % 3;
    int z0 = 3 * czg;                // home z cells: z0 .. z0+2

    if (tid == 0) { s_cnt = 0; s_hcnt = 0; }
    __syncthreads();

    int nb = nb_p[0];
    float inv_dt = 1.0f / dt_p[0];
    float ym0 = y_mean[0], ym1 = y_mean[1], ym2 = y_mean[2];
    float ys0 = y_std[0],  ys1 = y_std[1],  ys2 = y_std[2];

    int ln = tid & 63;
    unsigned long long lmask = (1ull << ln) - 1ull;

    // ---- distributed loss1: block b handles slice [b*SL, b*SL+SL) ----
    int SL = (N + NBLK - 1) / NBLK;       // 26 for N=6144
    float l1t = 0.0f;
    {
        int i1 = b * SL + tid;
        if (tid < SL && i1 < N) {
            float e0 = y[i1 * 3 + 0] - pred[i1 * 3 + 0];
            float e1 = y[i1 * 3 + 1] - pred[i1 * 3 + 1];
            float e2 = y[i1 * 3 + 2] - pred[i1 * 3 + 2];
            l1t = fmaf(e0, e0, fmaf(e1, e1, e2 * e2));
        }
    }

    // ================= phase A: scan + stage =================
    if (N == TPB * 6) {
        // fast path: batch y+mid_pos loads; defer mid_vel to write time
        float ppx[6], ppy[6], ppz[6];
        bool inN_[6];
        unsigned long long mN[6];
#pragma unroll
        for (int k = 0; k < 6; ++k) {
            int i = tid + k * TPB;
            float y0 = y[i * 3 + 0], y1 = y[i * 3 + 1], y2 = y[i * 3 + 2];
            float m0 = mid_pos[i * 3 + 0], m1 = mid_pos[i * 3 + 1], m2 = mid_pos[i * 3 + 2];
            bool fluid = (i >= nb);
            float i0 = fluid ? fmaf(y0, ys0, ym0) : 0.0f;
            float i1 = fluid ? fmaf(y1, ys1, ym1) : 0.0f;
            float i2 = fluid ? fmaf(y2, ys2, ym2) : 0.0f;
            ppx[k] = m0 + i0; ppy[k] = m1 + i1; ppz[k] = m2 + i2;
            int ix = cell_coord(ppx[k]), iy = cell_coord(ppy[k]), iz = cell_coord(ppz[k]);
            inN_[k] = (abs(ix - cx) <= 1) && (abs(iy - cy) <= 1) &&
                      (iz >= z0 - 1) && (iz <= z0 + 3);
            mN[k] = __ballot(inN_[k]);
        }
        int pre[6], tot = 0;
#pragma unroll
        for (int k = 0; k < 6; ++k) { pre[k] = tot; tot += __popcll(mN[k]); }
        int base = 0;
        if (ln == 0 && tot > 0) base = atomicAdd(&s_cnt, tot);
        base = __shfl(base, 0, 64);
#pragma unroll
        for (int k = 0; k < 6; ++k) {
            if (inN_[k]) {
                int slot = base + pre[k] + __popcll(mN[k] & lmask);
                if (slot < CAP) {
                    int i = tid + k * TPB;
                    float y0 = y[i * 3 + 0], y1 = y[i * 3 + 1], y2 = y[i * 3 + 2];
                    bool fluid = (i >= nb);
                    float i0 = fluid ? fmaf(y0, ys0, ym0) : 0.0f;
                    float i1 = fluid ? fmaf(y1, ys1, ym1) : 0.0f;
                    float i2 = fluid ? fmaf(y2, ys2, ym2) : 0.0f;
                    float v0 = mid_vel[i * 3 + 0] + i0 * inv_dt;
                    float v1 = mid_vel[i * 3 + 1] + i1 * inv_dt;
                    float v2 = mid_vel[i * 3 + 2] + i2 * inv_dt;
                    sh4[slot] = make_float4(ppx[k], ppy[k], ppz[k], v0);
                    sh2[slot] = make_float2(v1, v2);
                }
            }
        }
    } else {
        // generic path
        for (int i = tid; i < N; i += TPB) {
            float y0 = y[i * 3 + 0], y1 = y[i * 3 + 1], y2 = y[i * 3 + 2];
            float m0 = mid_pos[i * 3 + 0], m1 = mid_pos[i * 3 + 1], m2 = mid_pos[i * 3 + 2];
            bool fluid = (i >= nb);
            float i0 = fluid ? fmaf(y0, ys0, ym0) : 0.0f;
            float i1 = fluid ? fmaf(y1, ys1, ym1) : 0.0f;
            float i2 = fluid ? fmaf(y2, ys2, ym2) : 0.0f;
            float px = m0 + i0, py = m1 + i1, pz = m2 + i2;
            int ix = cell_coord(px), iy = cell_coord(py), iz = cell_coord(pz);
            bool inN = (abs(ix - cx) <= 1) && (abs(iy - cy) <= 1) &&
                       (iz >= z0 - 1) && (iz <= z0 + 3);
            unsigned long long mN = __ballot(inN);
            if (mN) {
                int base = 0;
                if (ln == 0) base = atomicAdd(&s_cnt, __popcll(mN));
                base = __shfl(base, 0, 64);
                if (inN) {
                    int slot = base + __popcll(mN & lmask);
                    if (slot < CAP) {
                        float v0 = mid_vel[i * 3 + 0] + i0 * inv_dt;
                        float v1 = mid_vel[i * 3 + 1] + i1 * inv_dt;
                        float v2 = mid_vel[i * 3 + 2] + i2 * inv_dt;
                        sh4[slot] = make_float4(px, py, pz, v0);
                        sh2[slot] = make_float2(v1, v2);
                    }
                }
            }
        }
    }
    __syncthreads();

    int T = s_cnt;
    bool staged = (T <= CAP);         // block-uniform

    float h = h_p[0], inv_h = 1.0f / h, h2 = h * h;
    float vol = vol_p[0];
    float sigma = 8.0f / (PI_F * h * h * h);
    int wv = tid >> 6;
    float acc = 0.0f;

    if (staged) {
        // home compaction from staged data (1 ballot + 1 atomic per wave)
        bool isH = false;
        if (tid < T) {
            float4 a = sh4[tid];
            int ix = cell_coord(a.x), iy = cell_coord(a.y), iz = cell_coord(a.z);
            isH = (ix == cx) && (iy == cy) && (iz >= z0) && (iz <= z0 + 2);
        }
        unsigned long long mH = __ballot(isH);
        if (mH) {
            int hb = 0;
            if (ln == 0) hb = atomicAdd(&s_hcnt, __popcll(mH));
            hb = __shfl(hb, 0, 64);
            if (isH) s_home[hb + __popcll(mH & lmask)] = (short)tid;
        }
        __syncthreads();
        int H = s_hcnt;

        // phase B: one wave per home particle vs staged neighborhood
        for (int hp = wv; hp < H; hp += NWAVE) {
            int hs = s_home[hp];
            float4 me4 = sh4[hs];
            float2 me2 = sh2[hs];
            float wacc = 0.0f, dacc = 0.0f;
            for (int j = ln; j < T; j += 64) {
                float4 a  = sh4[j];
                float2 b2 = sh2[j];
                pair_math(me4.x, me4.y, me4.z, me4.w, me2.x, me2.y,
                          a.x, a.y, a.z, a.w, b2.x, b2.y, inv_h, h2, wacc, dacc);
            }
            wacc = wave_reduce(wacc);
            dacc = wave_reduce(dacc);
            if (ln == 0) {
                acc += fabsf(fmaf(vol * sigma, wacc, -1.0f))
                     + fabsf(vol * (sigma / h) * dacc);
            }
        }
    } else {
        // overflow fallback (never for this input): O(N^2/waves) global path
        for (int i = wv; i < N; i += NWAVE) {
            float y0 = y[i * 3 + 0], y1 = y[i * 3 + 1], y2 = y[i * 3 + 2];
            bool fluid = (i >= nb);
            float i0 = fluid ? fmaf(y0, ys0, ym0) : 0.0f;
            float i1 = fluid ? fmaf(y1, ys1, ym1) : 0.0f;
            float i2 = fluid ? fmaf(y2, ys2, ym2) : 0.0f;
            float xix = mid_pos[i * 3 + 0] + i0;
            float xiy = mid_pos[i * 3 + 1] + i1;
            float xiz = mid_pos[i * 3 + 2] + i2;
            int ix = cell_coord(xix), iy = cell_coord(xiy), iz = cell_coord(xiz);
            bool isH = (ix == cx) && (iy == cy) && (iz >= z0) && (iz <= z0 + 2);
            if (!isH) continue;
            float vix = mid_vel[i * 3 + 0] + i0 * inv_dt;
            float viy = mid_vel[i * 3 + 1] + i1 * inv_dt;
            float viz = mid_vel[i * 3 + 2] + i2 * inv_dt;
            float wacc = 0.0f, dacc = 0.0f;
            for (int j = ln; j < N; j += 64) {
                float jy0 = y[j * 3 + 0], jy1 = y[j * 3 + 1], jy2 = y[j * 3 + 2];
                bool jf = (j >= nb);
                float j0 = jf ? fmaf(jy0, ys0, ym0) : 0.0f;
                float j1 = jf ? fmaf(jy1, ys1, ym1) : 0.0f;
                float j2 = jf ? fmaf(jy2, ys2, ym2) : 0.0f;
                float ax = mid_pos[j * 3 + 0] + j0;
                float ay = mid_pos[j * 3 + 1] + j1;
                float az = mid_pos[j * 3 + 2] + j2;
                float bx = mid_vel[j * 3 + 0] + j0 * inv_dt;
                float by = mid_vel[j * 3 + 1] + j1 * inv_dt;
                float bz = mid_vel[j * 3 + 2] + j2 * inv_dt;
                pair_math(xix, xiy, xiz, vix, viy, viz,
                          ax, ay, az, bx, by, bz, inv_h, h2, wacc, dacc);
            }
            wacc = wave_reduce(wacc);
            dacc = wave_reduce(dacc);
            if (ln == 0) {
                acc += fabsf(fmaf(vol * sigma, wacc, -1.0f))
                     + fabsf(vol * (sigma / h) * dacc);
            }
        }
        __syncthreads();
    }

    // fold pairs (0.1/N) and loss1 slice (1/N) into one block sum; plain store
    float v = acc * (0.1f * invN) + l1t * invN;
    float tot = block_reduce<TPB>(v, sred);
    if (tid == 0) part2[b] = tot;
}

// ---- K2: final combine (overwrites out[0] every call -> replay-safe) ----
__global__ void __launch_bounds__(256) k_final(
    const float* __restrict__ part2, float* __restrict__ out)
{
    __shared__ float sred[256 / 64];
    float s = 0.0f;
    for (int k = threadIdx.x; k < NBLK; k += 256) s += part2[k];
    float tot = block_reduce<256>(s, sred);
    if (threadIdx.x == 0) out[0] = tot;
}

extern "C" void kernel_launch(void* const* d_in, const int* in_sizes, int n_in,
                              void* d_out, int out_size, void* d_ws, size_t ws_size,
                              hipStream_t stream) {
    const float* pred    = (const float*)d_in[0];
    const float* y       = (const float*)d_in[1];
    const float* mid_pos = (const float*)d_in[2];
    const float* mid_vel = (const float*)d_in[3];
    const float* y_mean  = (const float*)d_in[4];
    const float* y_std   = (const float*)d_in[5];
    const float* h_p     = (const float*)d_in[6];
    const float* vol_p   = (const float*)d_in[7];
    // d_in[8] = rho_0 (cancels algebraically)
    const float* dt_p    = (const float*)d_in[9];
    const int*   nb_p    = (const int*)d_in[10];

    int N = in_sizes[0] / 3;
    float invN = 1.0f / (float)N;

    float* part2 = (float*)d_ws;

    k_main<<<NBLK, TPB, 0, stream>>>(pred, y, mid_pos, mid_vel, y_mean, y_std,
                                     h_p, vol_p, dt_p, nb_p, part2, N, invN);

    k_final<<<1, 256, 0, stream>>>(part2, (float*)d_out);
}